// Round 5
// baseline (521.798 us; speedup 1.0000x reference)
//
#include <hip/hip_runtime.h>

// ---------------------------------------------------------------------------
// WindowAttention fused kernel for MI355X (gfx950). FP32 I/O per reference:
//   x         [2048][49][256] f32      mask   [64][49][49] f32
//   qkv_w     [256][768] f32           qkv_b  [768] f32
//   proj_w    [256][256] f32           proj_b [256] f32
//   bias_table[169][8] f32             rel_index [2401] i32
//   out       [2048][49][256] f32
// Internals: bf16 MFMA (16x16x32), fp32 accumulate, exp2-domain softmax.
// v7: 38416-B LDS (4 blocks/CU with 8-KiB slack) by ELIMINATING the Os
//     buffer: projection is split by k-half. Per phase p, the 128 attn-out
//     cols are written into an overlay on wreg (P/q/k dead post-barrier),
//     half-projected with W2f k-steps p*4..p*4+3, and accumulated into
//     `out` via global read-modify-write (p0 store, p1 load+add+store).
//     v2-proven pieces restored: stride-40 aligned q/k (single b128 reads),
//     64-col-chunk fully-unrolled GEMM. Kept from v3-v5 (verified): shfl-
//     built V-frags (no V LDS), permuted-CB float4 softmax, streamed smax.
// ---------------------------------------------------------------------------

typedef __attribute__((ext_vector_type(8))) short v8s;   // 8 x bf16 (4 VGPRs)
typedef __attribute__((ext_vector_type(4))) float v4f;   // MFMA accumulator

__device__ __forceinline__ unsigned short f2bf(float f) {   // RNE f32->bf16
    union { float f; unsigned int i; } v; v.f = f;
    unsigned int x = v.i;
    return (unsigned short)((x + 0x7fffu + ((x >> 16) & 1u)) >> 16);
}
__device__ __forceinline__ unsigned int pk2bf(float a, float b) {
    return (unsigned int)f2bf(a) | ((unsigned int)f2bf(b) << 16);
}

#define NW1 196608              // W1f elements (48 tiles * 8 ksteps * 64 lanes * 8)
#define NW2 65536               // W2f elements (16 tiles * 8 ksteps * 64 lanes * 8)
#define NB1 768                 // B1v elements
#define NCB 1605632             // CBf elements (64*8*49*64), fp32
#define QSCALE_LOG2E 0.25503487f   // (1/sqrt(32)) * log2(e)
#define LOG2E 1.4426950408889634f

// ---------------------------------------------------------------------------
// Preprocessing (verbatim from v3-v5, harness-verified): fragment-linear bf16
// weights + fp32 combined bias/mask. CB inner dim is PERMUTED so lane l15
// reads its 4 softmax bias terms (cols nt*16+l15) as one float4 at l15*4.
// ---------------------------------------------------------------------------
__global__ void wattn_preproc(const float* __restrict__ qkv_w,
                              const float* __restrict__ qkv_b,
                              const float* __restrict__ proj_w,
                              const float* __restrict__ bias_table,
                              const float* __restrict__ mask,
                              const int* __restrict__ rel_index,
                              unsigned short* __restrict__ W1f,
                              unsigned short* __restrict__ W2f,
                              float* __restrict__ B1v,
                              float* __restrict__ CBf)
{
    const int idx = blockIdx.x * 256 + threadIdx.x;
    if (idx < NW1) {
        const int j = idx & 7, l = (idx >> 3) & 63, s = (idx >> 9) & 7, T = idx >> 12;
        const int k = s * 32 + (l >> 4) * 8 + j;
        const int n = T * 16 + (l & 15);
        const int hh = n / 96, sub = n % 96;
        const int col = (sub < 32) ? (hh * 32 + sub)
                      : (sub < 64) ? (256 + hh * 32 + (sub - 32))
                                   : (512 + hh * 32 + (sub - 64));
        float v = qkv_w[k * 768 + col];
        if (sub < 32) v *= QSCALE_LOG2E;
        W1f[idx] = f2bf(v);
    } else if (idx < NW1 + NW2) {
        const int t = idx - NW1;
        const int j = t & 7, l = (t >> 3) & 63, s = (t >> 9) & 7, T = t >> 12;
        const int k = s * 32 + (l >> 4) * 8 + j;
        const int n = T * 16 + (l & 15);
        W2f[t] = f2bf(proj_w[k * 256 + n]);
    } else if (idx < NW1 + NW2 + NB1) {
        const int n = idx - NW1 - NW2;
        const int hh = n / 96, sub = n % 96;
        const int col = (sub < 32) ? (hh * 32 + sub)
                      : (sub < 64) ? (256 + hh * 32 + (sub - 32))
                                   : (512 + hh * 32 + (sub - 64));
        float v = qkv_b[col];
        if (sub < 32) v *= QSCALE_LOG2E;
        B1v[n] = v;
    } else {
        const int t = idx - (NW1 + NW2 + NB1);
        if (t < NCB) {
            const int c = t & 63;
            const int rr = t >> 6;
            const int r = rr % 49;
            const int q2 = rr / 49;
            const int hh = q2 & 7;
            const int w = q2 >> 3;
            const int c_old = ((c & 3) << 4) | (c >> 2);   // permuted inner dim
            float v;
            if (c_old < 49) {
                const int ri = rel_index[r * 49 + c_old];
                v = (bias_table[ri * 8 + hh] + mask[(w * 49 + r) * 49 + c_old]) * LOG2E;
            } else {
                v = -1e30f;
            }
            CBf[t] = v;
        }
    }
}

// ---------------------------------------------------------------------------
// Main fused kernel: one block (4 waves) per window.
// LDS = xs 7056 + wreg 31360 = 38416 B (alloc 38912; 4 blocks/CU = 155648).
// Per-wave private region Wr (3920 shorts), overlaid lifetimes:
//   phase A: q [0,1960)  k [1960,3920)   ([49][40] each, single b128 reads)
//   phase B: P [0,3528)                  ([49][72], b128-aligned)
// Per p-phase, after a block barrier the first 6664 shorts of wreg become
// the shared attn-out half-tile Osp[49][136] feeding the half-projection.
// V never touches LDS (shfl-built PV B-frags from the QKV accumulator).
// ---------------------------------------------------------------------------
__global__ __launch_bounds__(256, 2)
void wattn_main(const float* __restrict__ x,
                const unsigned short* __restrict__ W1f,
                const float* __restrict__ B1v,
                const float* __restrict__ CB,
                const unsigned short* __restrict__ W2f,
                const float* __restrict__ proj_b,
                float* __restrict__ out)
{
    __shared__ __align__(16) unsigned short xs[49 * 72];     // x chunk bf16 [row][64+pad]
    __shared__ __align__(16) unsigned short wreg[4 * 3920];  // per-wave q/k then P
    unsigned short* const Osp = wreg;                        // overlay: attn-out [49][136]

    const int tid  = threadIdx.x;
    const int wave = tid >> 6;
    const int lane = tid & 63;
    const int quad = lane >> 4;
    const int l15  = lane & 15;
    const int b    = blockIdx.x;
    const int widx = b & 63;
    const float* xw = x + (long)b * 49 * 256;
    const v4f zero4 = {0.0f, 0.0f, 0.0f, 0.0f};
    unsigned short* const Wr = wreg + wave * 3920;

    // A-frag row bases into xs (clamped pad rows)
    int arow[4];
    #pragma unroll
    for (int mt = 0; mt < 4; ++mt) {
        int m = mt * 16 + l15; if (m > 48) m = 48;
        arow[mt] = m * 72 + quad * 8;
    }

    // ---- two GEMM+attention+half-proj phases; wave w owns head (p*4+w) ----
    #pragma unroll 1
    for (int p = 0; p < 2; ++p) {
        v4f acc[6][4];
        #pragma unroll
        for (int i = 0; i < 6; ++i)
            #pragma unroll
            for (int mt = 0; mt < 4; ++mt) acc[i][mt] = zero4;

        const int T0 = p * 24 + wave * 6;
        const unsigned short* bb = W1f + T0 * 4096 + lane * 8;

        // QKV GEMM over K=256 in four 64-col chunks (v2-proven structure)
        #pragma unroll 1
        for (int ch = 0; ch < 4; ++ch) {
            __syncthreads();   // previous consumers of xs (and Osp readers) done
            for (int i = tid; i < 784; i += 256) {
                const int r = i >> 4, cq = i & 15;
                const float4 v = *reinterpret_cast<const float4*>(xw + r * 256 + ch * 64 + cq * 4);
                ushort4 o;
                o.x = f2bf(v.x); o.y = f2bf(v.y); o.z = f2bf(v.z); o.w = f2bf(v.w);
                *reinterpret_cast<ushort4*>(&xs[r * 72 + cq * 4]) = o;
            }
            __syncthreads();
            #pragma unroll
            for (int s = 0; s < 2; ++s) {
                v8s afr[4];
                #pragma unroll
                for (int mt = 0; mt < 4; ++mt)
                    afr[mt] = *reinterpret_cast<const v8s*>(&xs[arow[mt] + s * 32]);
                v8s bfr[6];
                #pragma unroll
                for (int i = 0; i < 6; ++i)
                    bfr[i] = *reinterpret_cast<const v8s*>(bb + i * 4096 + (ch * 2 + s) * 512);
                #pragma unroll
                for (int i = 0; i < 6; ++i)
                    #pragma unroll
                    for (int mt = 0; mt < 4; ++mt)
                        acc[i][mt] = __builtin_amdgcn_mfma_f32_16x16x32_bf16(afr[mt], bfr[i], acc[i][mt], 0, 0, 0);
            }
        }
        // qkv bias
        #pragma unroll
        for (int i = 0; i < 6; ++i) {
            const float bv = B1v[(T0 + i) * 16 + l15];
            #pragma unroll
            for (int mt = 0; mt < 4; ++mt) {
                acc[i][mt].x += bv; acc[i][mt].y += bv; acc[i][mt].z += bv; acc[i][mt].w += bv;
            }
        }

        // pack V (acc tiles 4,5) into bf16 pairs; acc[4..5] dead after this
        unsigned int vpk[2][4][2];
        #pragma unroll
        for (int iv = 0; iv < 2; ++iv)
            #pragma unroll
            for (int mt = 0; mt < 4; ++mt) {
                vpk[iv][mt][0] = pk2bf(acc[4 + iv][mt][0], acc[4 + iv][mt][1]);
                vpk[iv][mt][1] = pk2bf(acc[4 + iv][mt][2], acc[4 + iv][mt][3]);
            }

        // ================= per-wave attention (no block barriers) =============
        const int h = p * 4 + wave;

        // scatter q,k (C-layout acc -> row-major [token][d], stride 40)
        #pragma unroll
        for (int i = 0; i < 4; ++i) {
            const int base = (i < 2) ? 0 : 1960;
            const int c = (i & 1) * 16 + l15;
            #pragma unroll
            for (int mt = 0; mt < 4; ++mt) {
                const int m0 = mt * 16 + quad * 4;
                #pragma unroll
                for (int r = 0; r < 4; ++r)
                    if (m0 + r < 49) Wr[base + (m0 + r) * 40 + c] = f2bf(acc[i][mt][r]);
            }
        }

        // preload ALL QK^T fragments (q/k region is overwritten by P below)
        v8s aq[4], bk[4];
        #pragma unroll
        for (int t = 0; t < 4; ++t) {
            int rq = t * 16 + l15; if (rq > 48) rq = 48;
            aq[t] = *reinterpret_cast<const v8s*>(&Wr[rq * 40 + quad * 8]);
            bk[t] = *reinterpret_cast<const v8s*>(&Wr[1960 + rq * 40 + quad * 8]);
        }

        // QK^T + softmax, streamed per m-tile; P (stride 72) overlays q/k
        const float* cbb = CB + ((long)widx * 8 + h) * 49 * 64;
        #pragma unroll 2
        for (int mt = 0; mt < 4; ++mt) {
            v4f sacc[4];
            #pragma unroll
            for (int nt = 0; nt < 4; ++nt)
                sacc[nt] = __builtin_amdgcn_mfma_f32_16x16x32_bf16(aq[mt], bk[nt], zero4, 0, 0, 0);
            #pragma unroll
            for (int r = 0; r < 4; ++r) {
                const int m = mt * 16 + quad * 4 + r;
                const int mc = m > 48 ? 48 : m;
                const float4 cb4 = *reinterpret_cast<const float4*>(cbb + mc * 64 + l15 * 4);
                float s0 = sacc[0][r] + cb4.x;
                float s1 = sacc[1][r] + cb4.y;
                float s2 = sacc[2][r] + cb4.z;
                float s3 = sacc[3][r] + cb4.w;
                float mx = fmaxf(fmaxf(s0, s1), fmaxf(s2, s3));
                #pragma unroll
                for (int off = 1; off < 16; off <<= 1) mx = fmaxf(mx, __shfl_xor(mx, off, 16));
                const float e0 = __builtin_exp2f(s0 - mx);
                const float e1 = __builtin_exp2f(s1 - mx);
                const float e2 = __builtin_exp2f(s2 - mx);
                const float e3 = __builtin_exp2f(s3 - mx);
                float sm = (e0 + e1) + (e2 + e3);
                #pragma unroll
                for (int off = 1; off < 16; off <<= 1) sm += __shfl_xor(sm, off, 16);
                const float rs = __builtin_amdgcn_rcpf(sm);
                if (m < 49) {
                    Wr[m * 72 + l15]      = f2bf(e0 * rs);
                    Wr[m * 72 + 16 + l15] = f2bf(e1 * rs);
                    Wr[m * 72 + 32 + l15] = f2bf(e2 * rs);
                    Wr[m * 72 + 48 + l15] = f2bf(e3 * rs);
                }
            }
        }

        // build PV B-frags from vpk via quad-permutes (no V LDS).
        const int srcA = ((quad & 1) << 5) + l15;
        v8s bvf[2][2];
        #pragma unroll
        for (int kt = 0; kt < 2; ++kt) {
            #pragma unroll
            for (int iv = 0; iv < 2; ++iv) {
                union { unsigned int u[4]; v8s v; } bw;
                #pragma unroll
                for (int hw = 0; hw < 2; ++hw) {
                    const unsigned int aA = (unsigned int)__shfl((int)vpk[iv][2 * kt][hw],     srcA);
                    const unsigned int bA = (unsigned int)__shfl((int)vpk[iv][2 * kt + 1][hw], srcA);
                    bw.u[hw] = (quad & 2) ? bA : aA;
                    const unsigned int aB = (unsigned int)__shfl((int)vpk[iv][2 * kt][hw],     srcA + 16);
                    const unsigned int bB = (unsigned int)__shfl((int)vpk[iv][2 * kt + 1][hw], srcA + 16);
                    bw.u[2 + hw] = (quad & 2) ? bB : aB;
                }
                bvf[kt][iv] = bw.v;
            }
        }

        // P @ V  (pad key tokens have P==0, so garbage V cols are inert)
        v4f oaccA[4][2];
        #pragma unroll
        for (int mt = 0; mt < 4; ++mt) {
            int mrc = mt * 16 + l15; if (mrc > 48) mrc = 48;
            v4f o0 = zero4, o1 = zero4;
            #pragma unroll
            for (int kt = 0; kt < 2; ++kt) {
                const v8s ap = *reinterpret_cast<const v8s*>(&Wr[mrc * 72 + kt * 32 + quad * 8]);
                o0 = __builtin_amdgcn_mfma_f32_16x16x32_bf16(ap, bvf[kt][0], o0, 0, 0, 0);
                o1 = __builtin_amdgcn_mfma_f32_16x16x32_bf16(ap, bvf[kt][1], o1, 0, 0, 0);
            }
            oaccA[mt][0] = o0; oaccA[mt][1] = o1;
        }

        // ---- phase-shared attn-out half-tile -> half-projection -> out RMW --
        __syncthreads();   // all waves done with wreg (P/q/k dead)
        #pragma unroll
        for (int mt = 0; mt < 4; ++mt) {
            #pragma unroll
            for (int n2 = 0; n2 < 2; ++n2) {
                const int c = wave * 32 + n2 * 16 + l15;   // col within this half
                #pragma unroll
                for (int r = 0; r < 4; ++r) {
                    const int m = mt * 16 + quad * 4 + r;
                    if (m < 49) Osp[m * 136 + c] = f2bf(oaccA[mt][n2][r]);
                }
            }
        }
        __syncthreads();   // Osp complete

        // half-projection: Osp[49(->64)][128] @ W2f[k = p*128 .. +128)
        v4f pacc[4][4];
        #pragma unroll
        for (int i = 0; i < 4; ++i)
            #pragma unroll
            for (int mt = 0; mt < 4; ++mt) pacc[i][mt] = zero4;

        int orow[4];
        #pragma unroll
        for (int mt = 0; mt < 4; ++mt) {
            int m = mt * 16 + l15; if (m > 48) m = 48;
            orow[mt] = m * 136 + quad * 8;
        }
        const unsigned short* wb = W2f + (wave * 4) * 4096 + lane * 8;

        #pragma unroll
        for (int ss = 0; ss < 4; ++ss) {
            v8s afr[4];
            #pragma unroll
            for (int mt = 0; mt < 4; ++mt)
                afr[mt] = *reinterpret_cast<const v8s*>(&Osp[orow[mt] + ss * 32]);
            #pragma unroll
            for (int i = 0; i < 4; ++i) {
                const v8s bfp = *reinterpret_cast<const v8s*>(wb + i * 4096 + (p * 4 + ss) * 512);
                #pragma unroll
                for (int mt = 0; mt < 4; ++mt)
                    pacc[i][mt] = __builtin_amdgcn_mfma_f32_16x16x32_bf16(afr[mt], bfp, pacc[i][mt], 0, 0, 0);
            }
        }

        #pragma unroll
        for (int i = 0; i < 4; ++i) {
            const int c = (wave * 4 + i) * 16 + l15;
            const float pb = proj_b[c];
            #pragma unroll
            for (int mt = 0; mt < 4; ++mt) {
                #pragma unroll
                for (int r = 0; r < 4; ++r) {
                    const int m = mt * 16 + quad * 4 + r;
                    if (m < 49) {
                        float* po = &out[((long)b * 49 + m) * 256 + c];
                        if (p == 0) *po = pacc[i][mt][r] + pb;
                        else        *po += pacc[i][mt][r];
                    }
                }
            }
        }
        // next p's first chunk barrier separates these Osp/out ops from the
        // next wreg scatter, so no extra barrier here.
    } // p
}

// ---------------------------------------------------------------------------
extern "C" void kernel_launch(void* const* d_in, const int* in_sizes, int n_in,
                              void* d_out, int out_size, void* d_ws, size_t ws_size,
                              hipStream_t stream)
{
    const float* x          = (const float*)d_in[0];
    const float* mask       = (const float*)d_in[1];
    const float* qkv_w      = (const float*)d_in[2];
    const float* qkv_b      = (const float*)d_in[3];
    const float* proj_w     = (const float*)d_in[4];
    const float* proj_b     = (const float*)d_in[5];
    const float* bias_table = (const float*)d_in[6];
    const int*   rel_index  = (const int*)d_in[7];
    float* out = (float*)d_out;

    char* ws = (char*)d_ws;
    unsigned short* W1f = (unsigned short*)(ws);             // 393216 B
    unsigned short* W2f = (unsigned short*)(ws + 393216);    // 131072 B
    float*          B1v = (float*)(ws + 524288);             //   3072 B
    float*          CBf = (float*)(ws + 527360);             // 6422528 B (total ~6.95 MB)

    // 196608 + 65536 + 768 + 1605632 = 1868544 = 7299 * 256 exactly
    wattn_preproc<<<7299, 256, 0, stream>>>(qkv_w, qkv_b, proj_w, bias_table, mask,
                                            rel_index, W1f, W2f, B1v, CBf);
    wattn_main<<<2048, 256, 0, stream>>>(x, W1f, B1v, CBf, W2f, proj_b, out);
}

// Round 6
// 411.203 us; speedup vs baseline: 1.2690x; 1.2690x over previous
//
#include <hip/hip_runtime.h>
#include <hip/hip_bf16.h>

// ---------------------------------------------------------------------------
// WindowAttention fused kernel for MI355X (gfx950). FP32 I/O per reference:
//   x         [2048][49][256] f32      mask   [64][49][49] f32
//   qkv_w     [256][768] f32           qkv_b  [768] f32
//   proj_w    [256][256] f32           proj_b [256] f32
//   bias_table[169][8] f32             rel_index [2401] i32
//   out       [2048][49][256] f32
// Internals: bf16 MFMA (16x16x32), fp32 accumulate, exp2-domain softmax.
// v8: BARRIER-MINIMAL design. Occupancy is hard-pinned at 2 blocks/CU
//     (proven across LDS 80K/54K/39K), so this version attacks exposed
//     latency instead: the QKV GEMM loads A-fragments DIRECTLY from global
//     x (L2-resident, 8 contiguous f32 -> v_cvt_pk_bf16_f32), eliminating
//     the x->LDS staging loop and ALL 16 staging barriers. Per-wave
//     private attention (v7-verified internals). ONE __syncthreads() per
//     block (before the v2-proven full projection from Os).
// ---------------------------------------------------------------------------

typedef __attribute__((ext_vector_type(8))) short v8s;   // 8 x bf16 (4 VGPRs)
typedef __attribute__((ext_vector_type(4))) float v4f;   // MFMA accumulator

__device__ __forceinline__ unsigned short f2bf(float f) {   // RNE f32->bf16
    union { float f; unsigned int i; } v; v.f = f;
    unsigned int x = v.i;
    return (unsigned short)((x + 0x7fffu + ((x >> 16) & 1u)) >> 16);
}
__device__ __forceinline__ unsigned int pk2bf(float a, float b) {
    return (unsigned int)f2bf(a) | ((unsigned int)f2bf(b) << 16);
}
// 8 f32 -> 8 bf16 via packed cvt (RNE, matches f2bf)
__device__ __forceinline__ v8s pack8(float4 a, float4 b) {
    union { __hip_bfloat162 h[4]; v8s v; } u;
    u.h[0] = __float22bfloat162_rn(make_float2(a.x, a.y));
    u.h[1] = __float22bfloat162_rn(make_float2(a.z, a.w));
    u.h[2] = __float22bfloat162_rn(make_float2(b.x, b.y));
    u.h[3] = __float22bfloat162_rn(make_float2(b.z, b.w));
    return u.v;
}

#define NW1 196608              // W1f elements (48 tiles * 8 ksteps * 64 lanes * 8)
#define NW2 65536               // W2f elements (16 tiles * 8 ksteps * 64 lanes * 8)
#define NB1 768                 // B1v elements
#define NCB 1605632             // CBf elements (64*8*49*64), fp32
#define QSCALE_LOG2E 0.25503487f   // (1/sqrt(32)) * log2(e)
#define LOG2E 1.4426950408889634f

// ---------------------------------------------------------------------------
// Preprocessing (verbatim, harness-verified): fragment-linear bf16 weights +
// fp32 combined bias/mask. CB inner dim PERMUTED so lane l15 reads its 4
// softmax bias terms (cols nt*16+l15) as one float4 at l15*4.
// ---------------------------------------------------------------------------
__global__ void wattn_preproc(const float* __restrict__ qkv_w,
                              const float* __restrict__ qkv_b,
                              const float* __restrict__ proj_w,
                              const float* __restrict__ bias_table,
                              const float* __restrict__ mask,
                              const int* __restrict__ rel_index,
                              unsigned short* __restrict__ W1f,
                              unsigned short* __restrict__ W2f,
                              float* __restrict__ B1v,
                              float* __restrict__ CBf)
{
    const int idx = blockIdx.x * 256 + threadIdx.x;
    if (idx < NW1) {
        const int j = idx & 7, l = (idx >> 3) & 63, s = (idx >> 9) & 7, T = idx >> 12;
        const int k = s * 32 + (l >> 4) * 8 + j;
        const int n = T * 16 + (l & 15);
        const int hh = n / 96, sub = n % 96;
        const int col = (sub < 32) ? (hh * 32 + sub)
                      : (sub < 64) ? (256 + hh * 32 + (sub - 32))
                                   : (512 + hh * 32 + (sub - 64));
        float v = qkv_w[k * 768 + col];
        if (sub < 32) v *= QSCALE_LOG2E;
        W1f[idx] = f2bf(v);
    } else if (idx < NW1 + NW2) {
        const int t = idx - NW1;
        const int j = t & 7, l = (t >> 3) & 63, s = (t >> 9) & 7, T = t >> 12;
        const int k = s * 32 + (l >> 4) * 8 + j;
        const int n = T * 16 + (l & 15);
        W2f[t] = f2bf(proj_w[k * 256 + n]);
    } else if (idx < NW1 + NW2 + NB1) {
        const int n = idx - NW1 - NW2;
        const int hh = n / 96, sub = n % 96;
        const int col = (sub < 32) ? (hh * 32 + sub)
                      : (sub < 64) ? (256 + hh * 32 + (sub - 32))
                                   : (512 + hh * 32 + (sub - 64));
        float v = qkv_b[col];
        if (sub < 32) v *= QSCALE_LOG2E;
        B1v[n] = v;
    } else {
        const int t = idx - (NW1 + NW2 + NB1);
        if (t < NCB) {
            const int c = t & 63;
            const int rr = t >> 6;
            const int r = rr % 49;
            const int q2 = rr / 49;
            const int hh = q2 & 7;
            const int w = q2 >> 3;
            const int c_old = ((c & 3) << 4) | (c >> 2);   // permuted inner dim
            float v;
            if (c_old < 49) {
                const int ri = rel_index[r * 49 + c_old];
                v = (bias_table[ri * 8 + hh] + mask[(w * 49 + r) * 49 + c_old]) * LOG2E;
            } else {
                v = -1e30f;
            }
            CBf[t] = v;
        }
    }
}

// ---------------------------------------------------------------------------
// Main fused kernel: one block (4 waves) per window.
// LDS = wreg 31360 + Os 25872 = 57232 B (2 blocks/CU).
// Per-wave private region Wr (3920 shorts), overlaid lifetimes:
//   phase A: q [0,1960)  k [1960,3920)   ([49][40] each, single b128 reads)
//   phase B: P [0,3528)                  ([49][72], b128-aligned)
// V never touches LDS (shfl-built PV B-frags). x never touches LDS (direct
// global f32 loads + packed cvt). ONE block barrier per kernel.
// ---------------------------------------------------------------------------
__global__ __launch_bounds__(256, 2)
void wattn_main(const float* __restrict__ x,
                const unsigned short* __restrict__ W1f,
                const float* __restrict__ B1v,
                const float* __restrict__ CB,
                const unsigned short* __restrict__ W2f,
                const float* __restrict__ proj_b,
                float* __restrict__ out)
{
    __shared__ __align__(16) unsigned short wreg[4 * 3920];  // per-wave q/k then P
    __shared__ __align__(16) unsigned short Os[49 * 264];    // attn out [token][256]

    const int tid  = threadIdx.x;
    const int wave = tid >> 6;
    const int lane = tid & 63;
    const int quad = lane >> 4;
    const int l15  = lane & 15;
    const int b    = blockIdx.x;
    const int widx = b & 63;
    const float* xw = x + (long)b * 49 * 256;
    const v4f zero4 = {0.0f, 0.0f, 0.0f, 0.0f};
    unsigned short* const Wr = wreg + wave * 3920;

    // A-frag row bases in GLOBAL x (f32 elems; clamped pad rows)
    int xrow[4];
    #pragma unroll
    for (int mt = 0; mt < 4; ++mt) {
        int m = mt * 16 + l15; if (m > 48) m = 48;
        xrow[mt] = m * 256 + quad * 8;
    }

    // ---- two GEMM+attention phases; wave w owns head (p*4 + w) ----
    #pragma unroll 1
    for (int p = 0; p < 2; ++p) {
        v4f acc[6][4];
        #pragma unroll
        for (int i = 0; i < 6; ++i)
            #pragma unroll
            for (int mt = 0; mt < 4; ++mt) acc[i][mt] = zero4;

        const int T0 = p * 24 + wave * 6;
        const unsigned short* bb = W1f + T0 * 4096 + lane * 8;

        // QKV GEMM over K=256: 8 k-steps, A-frags straight from global x.
        // No LDS, no barriers; compiler pipelines the L2-hot loads.
        #pragma unroll 2
        for (int ss = 0; ss < 8; ++ss) {
            v8s afr[4];
            #pragma unroll
            for (int mt = 0; mt < 4; ++mt) {
                const float* ap = xw + xrow[mt] + ss * 32;
                const float4 f0 = *reinterpret_cast<const float4*>(ap);
                const float4 f1 = *reinterpret_cast<const float4*>(ap + 4);
                afr[mt] = pack8(f0, f1);
            }
            v8s bfr[6];
            #pragma unroll
            for (int i = 0; i < 6; ++i)
                bfr[i] = *reinterpret_cast<const v8s*>(bb + i * 4096 + ss * 512);
            #pragma unroll
            for (int i = 0; i < 6; ++i)
                #pragma unroll
                for (int mt = 0; mt < 4; ++mt)
                    acc[i][mt] = __builtin_amdgcn_mfma_f32_16x16x32_bf16(afr[mt], bfr[i], acc[i][mt], 0, 0, 0);
        }
        // qkv bias
        #pragma unroll
        for (int i = 0; i < 6; ++i) {
            const float bv = B1v[(T0 + i) * 16 + l15];
            #pragma unroll
            for (int mt = 0; mt < 4; ++mt) {
                acc[i][mt].x += bv; acc[i][mt].y += bv; acc[i][mt].z += bv; acc[i][mt].w += bv;
            }
        }

        // pack V (acc tiles 4,5) into bf16 pairs; acc[4..5] dead after this
        unsigned int vpk[2][4][2];
        #pragma unroll
        for (int iv = 0; iv < 2; ++iv)
            #pragma unroll
            for (int mt = 0; mt < 4; ++mt) {
                vpk[iv][mt][0] = pk2bf(acc[4 + iv][mt][0], acc[4 + iv][mt][1]);
                vpk[iv][mt][1] = pk2bf(acc[4 + iv][mt][2], acc[4 + iv][mt][3]);
            }

        // ================= per-wave attention (no block barriers) =============
        const int h = p * 4 + wave;

        // scatter q,k (C-layout acc -> row-major [token][d], stride 40)
        #pragma unroll
        for (int i = 0; i < 4; ++i) {
            const int base = (i < 2) ? 0 : 1960;
            const int c = (i & 1) * 16 + l15;
            #pragma unroll
            for (int mt = 0; mt < 4; ++mt) {
                const int m0 = mt * 16 + quad * 4;
                #pragma unroll
                for (int r = 0; r < 4; ++r)
                    if (m0 + r < 49) Wr[base + (m0 + r) * 40 + c] = f2bf(acc[i][mt][r]);
            }
        }

        // preload ALL QK^T fragments (q/k region is overwritten by P below)
        v8s aq[4], bk[4];
        #pragma unroll
        for (int t = 0; t < 4; ++t) {
            int rq = t * 16 + l15; if (rq > 48) rq = 48;
            aq[t] = *reinterpret_cast<const v8s*>(&Wr[rq * 40 + quad * 8]);
            bk[t] = *reinterpret_cast<const v8s*>(&Wr[1960 + rq * 40 + quad * 8]);
        }

        // QK^T + softmax, streamed per m-tile; P (stride 72) overlays q/k
        const float* cbb = CB + ((long)widx * 8 + h) * 49 * 64;
        #pragma unroll 2
        for (int mt = 0; mt < 4; ++mt) {
            v4f sacc[4];
            #pragma unroll
            for (int nt = 0; nt < 4; ++nt)
                sacc[nt] = __builtin_amdgcn_mfma_f32_16x16x32_bf16(aq[mt], bk[nt], zero4, 0, 0, 0);
            #pragma unroll
            for (int r = 0; r < 4; ++r) {
                const int m = mt * 16 + quad * 4 + r;
                const int mc = m > 48 ? 48 : m;
                const float4 cb4 = *reinterpret_cast<const float4*>(cbb + mc * 64 + l15 * 4);
                float s0 = sacc[0][r] + cb4.x;
                float s1 = sacc[1][r] + cb4.y;
                float s2 = sacc[2][r] + cb4.z;
                float s3 = sacc[3][r] + cb4.w;
                float mx = fmaxf(fmaxf(s0, s1), fmaxf(s2, s3));
                #pragma unroll
                for (int off = 1; off < 16; off <<= 1) mx = fmaxf(mx, __shfl_xor(mx, off, 16));
                const float e0 = __builtin_exp2f(s0 - mx);
                const float e1 = __builtin_exp2f(s1 - mx);
                const float e2 = __builtin_exp2f(s2 - mx);
                const float e3 = __builtin_exp2f(s3 - mx);
                float sm = (e0 + e1) + (e2 + e3);
                #pragma unroll
                for (int off = 1; off < 16; off <<= 1) sm += __shfl_xor(sm, off, 16);
                const float rs = __builtin_amdgcn_rcpf(sm);
                if (m < 49) {
                    Wr[m * 72 + l15]      = f2bf(e0 * rs);
                    Wr[m * 72 + 16 + l15] = f2bf(e1 * rs);
                    Wr[m * 72 + 32 + l15] = f2bf(e2 * rs);
                    Wr[m * 72 + 48 + l15] = f2bf(e3 * rs);
                }
            }
        }

        // build PV B-frags from vpk via quad-permutes (no V LDS).
        const int srcA = ((quad & 1) << 5) + l15;
        v8s bvf[2][2];
        #pragma unroll
        for (int kt = 0; kt < 2; ++kt) {
            #pragma unroll
            for (int iv = 0; iv < 2; ++iv) {
                union { unsigned int u[4]; v8s v; } bw;
                #pragma unroll
                for (int hw = 0; hw < 2; ++hw) {
                    const unsigned int aA = (unsigned int)__shfl((int)vpk[iv][2 * kt][hw],     srcA);
                    const unsigned int bA = (unsigned int)__shfl((int)vpk[iv][2 * kt + 1][hw], srcA);
                    bw.u[hw] = (quad & 2) ? bA : aA;
                    const unsigned int aB = (unsigned int)__shfl((int)vpk[iv][2 * kt][hw],     srcA + 16);
                    const unsigned int bB = (unsigned int)__shfl((int)vpk[iv][2 * kt + 1][hw], srcA + 16);
                    bw.u[2 + hw] = (quad & 2) ? bB : aB;
                }
                bvf[kt][iv] = bw.v;
            }
        }

        // P @ V  (pad key tokens have P==0, so garbage V cols are inert)
        #pragma unroll
        for (int mt = 0; mt < 4; ++mt) {
            int mrc = mt * 16 + l15; if (mrc > 48) mrc = 48;
            v4f o0 = zero4, o1 = zero4;
            #pragma unroll
            for (int kt = 0; kt < 2; ++kt) {
                const v8s ap = *reinterpret_cast<const v8s*>(&Wr[mrc * 72 + kt * 32 + quad * 8]);
                o0 = __builtin_amdgcn_mfma_f32_16x16x32_bf16(ap, bvf[kt][0], o0, 0, 0, 0);
                o1 = __builtin_amdgcn_mfma_f32_16x16x32_bf16(ap, bvf[kt][1], o1, 0, 0, 0);
            }
            #pragma unroll
            for (int r = 0; r < 4; ++r) {
                const int m = mt * 16 + quad * 4 + r;
                if (m < 49) {
                    Os[m * 264 + h * 32 + l15]      = f2bf(o0[r]);
                    Os[m * 264 + h * 32 + 16 + l15] = f2bf(o1[r]);
                }
            }
        }
    } // p

    __syncthreads();   // the ONLY block barrier: all Os columns complete

    // ---- projection: Os[49(->64)][256] @ proj_w -> out (fp32) ----
    v4f pacc[4][4];
    #pragma unroll
    for (int i = 0; i < 4; ++i)
        #pragma unroll
        for (int mt = 0; mt < 4; ++mt) pacc[i][mt] = zero4;

    int orow[4];
    #pragma unroll
    for (int mt = 0; mt < 4; ++mt) {
        int m = mt * 16 + l15; if (m > 48) m = 48;
        orow[mt] = m * 264 + quad * 8;
    }
    const unsigned short* wb = W2f + (wave * 4) * 4096 + lane * 8;

    #pragma unroll 2
    for (int s = 0; s < 8; ++s) {
        v8s afr[4];
        #pragma unroll
        for (int mt = 0; mt < 4; ++mt)
            afr[mt] = *reinterpret_cast<const v8s*>(&Os[orow[mt] + s * 32]);
        #pragma unroll
        for (int i = 0; i < 4; ++i) {
            const v8s bfp = *reinterpret_cast<const v8s*>(wb + i * 4096 + s * 512);
            #pragma unroll
            for (int mt = 0; mt < 4; ++mt)
                pacc[i][mt] = __builtin_amdgcn_mfma_f32_16x16x32_bf16(afr[mt], bfp, pacc[i][mt], 0, 0, 0);
        }
    }

    #pragma unroll
    for (int i = 0; i < 4; ++i) {
        const int c = (wave * 4 + i) * 16 + l15;
        const float pb = proj_b[c];
        #pragma unroll
        for (int mt = 0; mt < 4; ++mt) {
            #pragma unroll
            for (int r = 0; r < 4; ++r) {
                const int m = mt * 16 + quad * 4 + r;
                if (m < 49) out[((long)b * 49 + m) * 256 + c] = pacc[i][mt][r] + pb;
            }
        }
    }
}

// ---------------------------------------------------------------------------
extern "C" void kernel_launch(void* const* d_in, const int* in_sizes, int n_in,
                              void* d_out, int out_size, void* d_ws, size_t ws_size,
                              hipStream_t stream)
{
    const float* x          = (const float*)d_in[0];
    const float* mask       = (const float*)d_in[1];
    const float* qkv_w      = (const float*)d_in[2];
    const float* qkv_b      = (const float*)d_in[3];
    const float* proj_w     = (const float*)d_in[4];
    const float* proj_b     = (const float*)d_in[5];
    const float* bias_table = (const float*)d_in[6];
    const int*   rel_index  = (const int*)d_in[7];
    float* out = (float*)d_out;

    char* ws = (char*)d_ws;
    unsigned short* W1f = (unsigned short*)(ws);             // 393216 B
    unsigned short* W2f = (unsigned short*)(ws + 393216);    // 131072 B
    float*          B1v = (float*)(ws + 524288);             //   3072 B
    float*          CBf = (float*)(ws + 527360);             // 6422528 B (total ~6.95 MB)

    // 196608 + 65536 + 768 + 1605632 = 1868544 = 7299 * 256 exactly
    wattn_preproc<<<7299, 256, 0, stream>>>(qkv_w, qkv_b, proj_w, bias_table, mask,
                                            rel_index, W1f, W2f, B1v, CBf);
    wattn_main<<<2048, 256, 0, stream>>>(x, W1f, B1v, CBf, W2f, proj_b, out);
}

// Round 7
// 410.351 us; speedup vs baseline: 1.2716x; 1.0021x over previous
//
#include <hip/hip_runtime.h>

// ---------------------------------------------------------------------------
// WindowAttention fused kernel for MI355X (gfx950). FP32 I/O per reference.
// Internals: bf16 MFMA (16x16x32), fp32 accumulate, exp2-domain softmax.
// v9: REGISTER-BUDGET design. Diagnosis: MFMA accumulators live in AGPRs
//     against the unified 512-reg/SIMD file; acc[6][4]=96 AGPR + ~110 VGPR
//     pinned every prior version at 2 waves/SIMD (the invariant 22% occ).
//     Fix: stage full x ONCE to LDS (re-read 4x), split QKV GEMM into
//     kv-pass (acc 64) then q-pass (acc 32); PV outputs held in regs;
//     Os overlays the dead xs region for the projection. Peak live ~145
//     <= 170 => __launch_bounds__(256,3) spill-free => 3 waves/SIMD.
//     LDS 54096 B. 3 barriers/block.
// ---------------------------------------------------------------------------

typedef __attribute__((ext_vector_type(8))) short v8s;   // 8 x bf16 (4 VGPRs)
typedef __attribute__((ext_vector_type(4))) short v4s;   // 4 x bf16
typedef __attribute__((ext_vector_type(4))) float v4f;   // MFMA accumulator

__device__ __forceinline__ unsigned short f2bf(float f) {   // RNE f32->bf16
    union { float f; unsigned int i; } v; v.f = f;
    unsigned int x = v.i;
    return (unsigned short)((x + 0x7fffu + ((x >> 16) & 1u)) >> 16);
}
__device__ __forceinline__ unsigned int pk2bf(float a, float b) {
    return (unsigned int)f2bf(a) | ((unsigned int)f2bf(b) << 16);
}

#define NW1 196608              // W1f elements (48 tiles * 8 ksteps * 64 lanes * 8)
#define NW2 65536               // W2f elements (16 tiles * 8 ksteps * 64 lanes * 8)
#define NB1 768                 // B1v elements
#define NCB 1605632             // CBf elements (64*8*49*64), fp32
#define QSCALE_LOG2E 0.25503487f   // (1/sqrt(32)) * log2(e)
#define LOG2E 1.4426950408889634f

// ---------------------------------------------------------------------------
// Preprocessing (verbatim, harness-verified): fragment-linear bf16 weights +
// fp32 combined bias/mask. CB inner dim PERMUTED so lane l15 reads its 4
// softmax bias terms (cols nt*16+l15) as one float4 at l15*4.
// ---------------------------------------------------------------------------
__global__ void wattn_preproc(const float* __restrict__ qkv_w,
                              const float* __restrict__ qkv_b,
                              const float* __restrict__ proj_w,
                              const float* __restrict__ bias_table,
                              const float* __restrict__ mask,
                              const int* __restrict__ rel_index,
                              unsigned short* __restrict__ W1f,
                              unsigned short* __restrict__ W2f,
                              float* __restrict__ B1v,
                              float* __restrict__ CBf)
{
    const int idx = blockIdx.x * 256 + threadIdx.x;
    if (idx < NW1) {
        const int j = idx & 7, l = (idx >> 3) & 63, s = (idx >> 9) & 7, T = idx >> 12;
        const int k = s * 32 + (l >> 4) * 8 + j;
        const int n = T * 16 + (l & 15);
        const int hh = n / 96, sub = n % 96;
        const int col = (sub < 32) ? (hh * 32 + sub)
                      : (sub < 64) ? (256 + hh * 32 + (sub - 32))
                                   : (512 + hh * 32 + (sub - 64));
        float v = qkv_w[k * 768 + col];
        if (sub < 32) v *= QSCALE_LOG2E;
        W1f[idx] = f2bf(v);
    } else if (idx < NW1 + NW2) {
        const int t = idx - NW1;
        const int j = t & 7, l = (t >> 3) & 63, s = (t >> 9) & 7, T = t >> 12;
        const int k = s * 32 + (l >> 4) * 8 + j;
        const int n = T * 16 + (l & 15);
        W2f[t] = f2bf(proj_w[k * 256 + n]);
    } else if (idx < NW1 + NW2 + NB1) {
        const int n = idx - NW1 - NW2;
        const int hh = n / 96, sub = n % 96;
        const int col = (sub < 32) ? (hh * 32 + sub)
                      : (sub < 64) ? (256 + hh * 32 + (sub - 32))
                                   : (512 + hh * 32 + (sub - 64));
        float v = qkv_b[col];
        if (sub < 32) v *= QSCALE_LOG2E;
        B1v[n] = v;
    } else {
        const int t = idx - (NW1 + NW2 + NB1);
        if (t < NCB) {
            const int c = t & 63;
            const int rr = t >> 6;
            const int r = rr % 49;
            const int q2 = rr / 49;
            const int hh = q2 & 7;
            const int w = q2 >> 3;
            const int c_old = ((c & 3) << 4) | (c >> 2);   // permuted inner dim
            float v;
            if (c_old < 49) {
                const int ri = rel_index[r * 49 + c_old];
                v = (bias_table[ri * 8 + hh] + mask[(w * 49 + r) * 49 + c_old]) * LOG2E;
            } else {
                v = -1e30f;
            }
            CBf[t] = v;
        }
    }
}

// ---------------------------------------------------------------------------
// One phase: kv-GEMM -> scatter k / pack V -> q-GEMM -> scatter q ->
// QK^T -> softmax -> P -> PV (output kept in registers).
// Wr layout (per-wave, 3528 shorts): q [0,1764) k [1764,3528) stride 36;
// P [0,3528) stride 72 (overlays q/k after frag preload).
// ---------------------------------------------------------------------------
template<int PH>
__device__ __forceinline__ void attn_phase(
    const unsigned short* __restrict__ xs,
    unsigned short* __restrict__ Wr,
    const unsigned short* __restrict__ W1f,
    const float* __restrict__ B1v,
    const float* __restrict__ CB,
    const int wave, const int lane, const int quad, const int l15,
    const int widx, const int (&arow)[4],
    v4f (&oacc)[4][2])
{
    const v4f zero4 = {0.0f, 0.0f, 0.0f, 0.0f};
    const int T0 = PH * 24 + wave * 6;
    const unsigned short* bb = W1f + T0 * 4096 + lane * 8;

    // ---- kv-GEMM: B tiles T0+2..T0+5 -> acc[0..1]=k, acc[2..3]=v ----
    v4f acc[4][4];
    #pragma unroll
    for (int i = 0; i < 4; ++i)
        #pragma unroll
        for (int mt = 0; mt < 4; ++mt) acc[i][mt] = zero4;
    #pragma unroll 1
    for (int ss = 0; ss < 8; ++ss) {
        v8s afr[4];
        #pragma unroll
        for (int mt = 0; mt < 4; ++mt)
            afr[mt] = *reinterpret_cast<const v8s*>(&xs[arow[mt] + ss * 32]);
        v8s bfr[4];
        #pragma unroll
        for (int i = 0; i < 4; ++i)
            bfr[i] = *reinterpret_cast<const v8s*>(bb + (2 + i) * 4096 + ss * 512);
        #pragma unroll
        for (int i = 0; i < 4; ++i)
            #pragma unroll
            for (int mt = 0; mt < 4; ++mt)
                acc[i][mt] = __builtin_amdgcn_mfma_f32_16x16x32_bf16(afr[mt], bfr[i], acc[i][mt], 0, 0, 0);
    }
    // bias k,v
    #pragma unroll
    for (int i = 0; i < 4; ++i) {
        const float bv = B1v[(T0 + 2 + i) * 16 + l15];
        #pragma unroll
        for (int mt = 0; mt < 4; ++mt) {
            acc[i][mt].x += bv; acc[i][mt].y += bv; acc[i][mt].z += bv; acc[i][mt].w += bv;
        }
    }
    // pack V (acc[2..3]) into bf16 pairs
    unsigned int vpk[2][4][2];
    #pragma unroll
    for (int iv = 0; iv < 2; ++iv)
        #pragma unroll
        for (int mt = 0; mt < 4; ++mt) {
            vpk[iv][mt][0] = pk2bf(acc[2 + iv][mt][0], acc[2 + iv][mt][1]);
            vpk[iv][mt][1] = pk2bf(acc[2 + iv][mt][2], acc[2 + iv][mt][3]);
        }
    // scatter k (acc[0..1]) -> Wr[1764 + row*36 + c]
    #pragma unroll
    for (int i = 0; i < 2; ++i) {
        const int c = i * 16 + l15;
        #pragma unroll
        for (int mt = 0; mt < 4; ++mt) {
            const int m0 = mt * 16 + quad * 4;
            #pragma unroll
            for (int r = 0; r < 4; ++r)
                if (m0 + r < 49) Wr[1764 + (m0 + r) * 36 + c] = f2bf(acc[i][mt][r]);
        }
    }

    // ---- q-GEMM: B tiles T0+0..T0+1 -> qac (acc[] dead now) ----
    v4f qac[2][4];
    #pragma unroll
    for (int i = 0; i < 2; ++i)
        #pragma unroll
        for (int mt = 0; mt < 4; ++mt) qac[i][mt] = zero4;
    #pragma unroll 2
    for (int ss = 0; ss < 8; ++ss) {
        v8s afr[4];
        #pragma unroll
        for (int mt = 0; mt < 4; ++mt)
            afr[mt] = *reinterpret_cast<const v8s*>(&xs[arow[mt] + ss * 32]);
        v8s bfr[2];
        #pragma unroll
        for (int i = 0; i < 2; ++i)
            bfr[i] = *reinterpret_cast<const v8s*>(bb + i * 4096 + ss * 512);
        #pragma unroll
        for (int i = 0; i < 2; ++i)
            #pragma unroll
            for (int mt = 0; mt < 4; ++mt)
                qac[i][mt] = __builtin_amdgcn_mfma_f32_16x16x32_bf16(afr[mt], bfr[i], qac[i][mt], 0, 0, 0);
    }
    #pragma unroll
    for (int i = 0; i < 2; ++i) {
        const float bv = B1v[(T0 + i) * 16 + l15];
        #pragma unroll
        for (int mt = 0; mt < 4; ++mt) {
            qac[i][mt].x += bv; qac[i][mt].y += bv; qac[i][mt].z += bv; qac[i][mt].w += bv;
        }
    }
    // scatter q -> Wr[row*36 + c]
    #pragma unroll
    for (int i = 0; i < 2; ++i) {
        const int c = i * 16 + l15;
        #pragma unroll
        for (int mt = 0; mt < 4; ++mt) {
            const int m0 = mt * 16 + quad * 4;
            #pragma unroll
            for (int r = 0; r < 4; ++r)
                if (m0 + r < 49) Wr[(m0 + r) * 36 + c] = f2bf(qac[i][mt][r]);
        }
    }

    // preload ALL QK^T fragments (q/k region overwritten by P below)
    v8s aq[4], bk[4];
    #pragma unroll
    for (int t = 0; t < 4; ++t) {
        int rq = t * 16 + l15; if (rq > 48) rq = 48;
        const int qo = rq * 36 + quad * 8;
        const v4s qlo = *reinterpret_cast<const v4s*>(&Wr[qo]);
        const v4s qhi = *reinterpret_cast<const v4s*>(&Wr[qo + 4]);
        aq[t] = __builtin_shufflevector(qlo, qhi, 0, 1, 2, 3, 4, 5, 6, 7);
        const v4s klo = *reinterpret_cast<const v4s*>(&Wr[1764 + qo]);
        const v4s khi = *reinterpret_cast<const v4s*>(&Wr[1764 + qo + 4]);
        bk[t] = __builtin_shufflevector(klo, khi, 0, 1, 2, 3, 4, 5, 6, 7);
    }

    // QK^T + softmax, streamed per m-tile; P (stride 72) overlays q/k
    const float* cbb = CB + ((long)widx * 8 + PH * 4 + wave) * 49 * 64;
    #pragma unroll 2
    for (int mt = 0; mt < 4; ++mt) {
        v4f sacc[4];
        #pragma unroll
        for (int nt = 0; nt < 4; ++nt)
            sacc[nt] = __builtin_amdgcn_mfma_f32_16x16x32_bf16(aq[mt], bk[nt], zero4, 0, 0, 0);
        #pragma unroll
        for (int r = 0; r < 4; ++r) {
            const int m = mt * 16 + quad * 4 + r;
            const int mc = m > 48 ? 48 : m;
            const float4 cb4 = *reinterpret_cast<const float4*>(cbb + mc * 64 + l15 * 4);
            float s0 = sacc[0][r] + cb4.x;
            float s1 = sacc[1][r] + cb4.y;
            float s2 = sacc[2][r] + cb4.z;
            float s3 = sacc[3][r] + cb4.w;
            float mx = fmaxf(fmaxf(s0, s1), fmaxf(s2, s3));
            #pragma unroll
            for (int off = 1; off < 16; off <<= 1) mx = fmaxf(mx, __shfl_xor(mx, off, 16));
            const float e0 = __builtin_exp2f(s0 - mx);
            const float e1 = __builtin_exp2f(s1 - mx);
            const float e2 = __builtin_exp2f(s2 - mx);
            const float e3 = __builtin_exp2f(s3 - mx);
            float sm = (e0 + e1) + (e2 + e3);
            #pragma unroll
            for (int off = 1; off < 16; off <<= 1) sm += __shfl_xor(sm, off, 16);
            const float rs = __builtin_amdgcn_rcpf(sm);
            if (m < 49) {
                Wr[m * 72 + l15]      = f2bf(e0 * rs);
                Wr[m * 72 + 16 + l15] = f2bf(e1 * rs);
                Wr[m * 72 + 32 + l15] = f2bf(e2 * rs);
                Wr[m * 72 + 48 + l15] = f2bf(e3 * rs);
            }
        }
    }

    // build PV B-frags from vpk via quad-permutes (no V LDS)
    const int srcA = ((quad & 1) << 5) + l15;
    v8s bvf[2][2];
    #pragma unroll
    for (int kt = 0; kt < 2; ++kt) {
        #pragma unroll
        for (int iv = 0; iv < 2; ++iv) {
            union { unsigned int u[4]; v8s v; } bw;
            #pragma unroll
            for (int hw = 0; hw < 2; ++hw) {
                const unsigned int aA = (unsigned int)__shfl((int)vpk[iv][2 * kt][hw],     srcA);
                const unsigned int bA = (unsigned int)__shfl((int)vpk[iv][2 * kt + 1][hw], srcA);
                bw.u[hw] = (quad & 2) ? bA : aA;
                const unsigned int aB = (unsigned int)__shfl((int)vpk[iv][2 * kt][hw],     srcA + 16);
                const unsigned int bB = (unsigned int)__shfl((int)vpk[iv][2 * kt + 1][hw], srcA + 16);
                bw.u[2 + hw] = (quad & 2) ? bB : aB;
            }
            bvf[kt][iv] = bw.v;
        }
    }

    // P @ V -> oacc (pad key tokens have P==0, garbage V cols inert)
    #pragma unroll
    for (int mt = 0; mt < 4; ++mt) {
        int mrc = mt * 16 + l15; if (mrc > 48) mrc = 48;
        v4f o0 = zero4, o1 = zero4;
        #pragma unroll
        for (int kt = 0; kt < 2; ++kt) {
            const v8s ap = *reinterpret_cast<const v8s*>(&Wr[mrc * 72 + kt * 32 + quad * 8]);
            o0 = __builtin_amdgcn_mfma_f32_16x16x32_bf16(ap, bvf[kt][0], o0, 0, 0, 0);
            o1 = __builtin_amdgcn_mfma_f32_16x16x32_bf16(ap, bvf[kt][1], o1, 0, 0, 0);
        }
        oacc[mt][0] = o0; oacc[mt][1] = o1;
    }
}

// ---------------------------------------------------------------------------
// Main fused kernel: one block (4 waves) per window.
// LDS = xs 25872 + wreg 28224 = 54096 B. 3 barriers total.
// ---------------------------------------------------------------------------
__global__ __launch_bounds__(256, 3)
void wattn_main(const float* __restrict__ x,
                const unsigned short* __restrict__ W1f,
                const float* __restrict__ B1v,
                const float* __restrict__ CB,
                const unsigned short* __restrict__ W2f,
                const float* __restrict__ proj_b,
                float* __restrict__ out)
{
    __shared__ __align__(16) unsigned short xs[49 * 264];    // x bf16; later Os
    __shared__ __align__(16) unsigned short wreg[4 * 3528];  // per-wave q/k then P

    const int tid  = threadIdx.x;
    const int wave = tid >> 6;
    const int lane = tid & 63;
    const int quad = lane >> 4;
    const int l15  = lane & 15;
    const int b    = blockIdx.x;
    const int widx = b & 63;
    const float* xw = x + (long)b * 49 * 256;
    unsigned short* const Wr = wreg + wave * 3528;

    // A-frag row bases into xs (clamped pad rows), stride 264
    int arow[4];
    #pragma unroll
    for (int mt = 0; mt < 4; ++mt) {
        int m = mt * 16 + l15; if (m > 48) m = 48;
        arow[mt] = m * 264 + quad * 8;
    }

    // ---- stage full x [49][256] -> bf16 xs (once) ----
    for (int i = tid; i < 3136; i += 256) {
        const int r = i >> 6, cq = i & 63;
        const float4 v = *reinterpret_cast<const float4*>(xw + r * 256 + cq * 4);
        ushort4 o;
        o.x = f2bf(v.x); o.y = f2bf(v.y); o.z = f2bf(v.z); o.w = f2bf(v.w);
        *reinterpret_cast<ushort4*>(&xs[r * 264 + cq * 4]) = o;
    }
    __syncthreads();

    // ---- two phases, outputs held in registers ----
    v4f oacc0[4][2], oacc1[4][2];
    attn_phase<0>(xs, Wr, W1f, B1v, CB, wave, lane, quad, l15, widx, arow, oacc0);
    attn_phase<1>(xs, Wr, W1f, B1v, CB, wave, lane, quad, l15, widx, arow, oacc1);

    __syncthreads();   // all waves done reading xs -> Os may overlay it
    unsigned short* const Os = xs;   // [49][264], cols 0..255 valid

    #pragma unroll
    for (int mt = 0; mt < 4; ++mt) {
        #pragma unroll
        for (int n2 = 0; n2 < 2; ++n2) {
            const int c0 = wave * 32 + n2 * 16 + l15;         // phase-0 head cols
            #pragma unroll
            for (int r = 0; r < 4; ++r) {
                const int m = mt * 16 + quad * 4 + r;
                if (m < 49) {
                    Os[m * 264 + c0]       = f2bf(oacc0[mt][n2][r]);
                    Os[m * 264 + 128 + c0] = f2bf(oacc1[mt][n2][r]);
                }
            }
        }
    }
    __syncthreads();   // Os complete

    // ---- projection: Os[49(->64)][256] @ proj_w -> out (fp32) ----
    v4f pacc[4][4];
    #pragma unroll
    for (int i = 0; i < 4; ++i)
        #pragma unroll
        for (int mt = 0; mt < 4; ++mt) pacc[i][mt] = {0.0f, 0.0f, 0.0f, 0.0f};

    int orow[4];
    #pragma unroll
    for (int mt = 0; mt < 4; ++mt) {
        int m = mt * 16 + l15; if (m > 48) m = 48;
        orow[mt] = m * 264 + quad * 8;
    }
    const unsigned short* wb = W2f + (wave * 4) * 4096 + lane * 8;

    #pragma unroll 2
    for (int s = 0; s < 8; ++s) {
        v8s afr[4];
        #pragma unroll
        for (int mt = 0; mt < 4; ++mt)
            afr[mt] = *reinterpret_cast<const v8s*>(&Os[orow[mt] + s * 32]);
        #pragma unroll
        for (int i = 0; i < 4; ++i) {
            const v8s bfp = *reinterpret_cast<const v8s*>(wb + i * 4096 + s * 512);
            #pragma unroll
            for (int mt = 0; mt < 4; ++mt)
                pacc[i][mt] = __builtin_amdgcn_mfma_f32_16x16x32_bf16(afr[mt], bfp, pacc[i][mt], 0, 0, 0);
        }
    }

    #pragma unroll
    for (int i = 0; i < 4; ++i) {
        const int c = (wave * 4 + i) * 16 + l15;
        const float pb = proj_b[c];
        #pragma unroll
        for (int mt = 0; mt < 4; ++mt) {
            #pragma unroll
            for (int r = 0; r < 4; ++r) {
                const int m = mt * 16 + quad * 4 + r;
                if (m < 49) out[((long)b * 49 + m) * 256 + c] = pacc[i][mt][r] + pb;
            }
        }
    }
}

// ---------------------------------------------------------------------------
extern "C" void kernel_launch(void* const* d_in, const int* in_sizes, int n_in,
                              void* d_out, int out_size, void* d_ws, size_t ws_size,
                              hipStream_t stream)
{
    const float* x          = (const float*)d_in[0];
    const float* mask       = (const float*)d_in[1];
    const float* qkv_w      = (const float*)d_in[2];
    const float* qkv_b      = (const float*)d_in[3];
    const float* proj_w     = (const float*)d_in[4];
    const float* proj_b     = (const float*)d_in[5];
    const float* bias_table = (const float*)d_in[6];
    const int*   rel_index  = (const int*)d_in[7];
    float* out = (float*)d_out;

    char* ws = (char*)d_ws;
    unsigned short* W1f = (unsigned short*)(ws);             // 393216 B
    unsigned short* W2f = (unsigned short*)(ws + 393216);    // 131072 B
    float*          B1v = (float*)(ws + 524288);             //   3072 B
    float*          CBf = (float*)(ws + 527360);             // 6422528 B (total ~6.95 MB)

    // 196608 + 65536 + 768 + 1605632 = 1868544 = 7299 * 256 exactly
    wattn_preproc<<<7299, 256, 0, stream>>>(qkv_w, qkv_b, proj_w, bias_table, mask,
                                            rel_index, W1f, W2f, B1v, CBf);
    wattn_main<<<2048, 256, 0, stream>>>(x, W1f, B1v, CBf, W2f, proj_b, out);
}